// Round 9
// baseline (55.491 us; speedup 1.0000x reference)
//
#include <hip/hip_runtime.h>
#include <hip/hip_bf16.h>
#include <math.h>

#define LATENT 16
#define NREP 10
#define NSTEPS 10
#define NTERMS 169          // 1 + 16 + 136 + 16
#define NCHUNK 7            // 7 x K=32 = 224 k-slots (168 live + dead pads; ONE folded)
#define DT 0.01f
#define ASCALE 1024.0f      // exact pow2: lifts f16 A-coeffs out of subnormal range
#define INV_ASCALE (1.0f/1024.0f)

#define WS_A_BYTES (NREP * NCHUNK * 64 * 16)     // 71680
#define WS_C0_OFF  WS_A_BYTES
#define WS_TOTAL   (WS_A_BYTES + NREP * LATENT * 4)

typedef _Float16 h2 __attribute__((ext_vector_type(2)));
typedef _Float16 half8 __attribute__((ext_vector_type(8)));
typedef __fp16 fp16x2 __attribute__((ext_vector_type(2)));
typedef __attribute__((ext_vector_type(4))) float f32x4;
typedef int int4v __attribute__((ext_vector_type(4)));   // asm-pinnable 128-bit

union FragH  { half8 v; h2 p[4]; int4v i4; };
union FragHE { half8 v; _Float16 e[8]; int4v i4; };

#define SW(x) __builtin_shufflevector((x), (x), 1, 0)

// v_cvt_pkrtz_f16_f32 with a bit-exact type bridge (__fp16x2 -> _Float16x2)
__device__ __forceinline__ h2 pkrtz(float a, float b) {
    fp16x2 r = __builtin_amdgcn_cvt_pkrtz(a, b);
    return __builtin_bit_cast(h2, r);
}

// shfl_xor on a packed f16 pair (bit-exact through int)
__device__ __forceinline__ h2 shfl_xor_h2(h2 v, int mask) {
    int i = __builtin_bit_cast(int, v);
    return __builtin_bit_cast(h2, __shfl_xor(i, mask));
}

// ---------------- slot -> library row mapping (IDENTICAL to rounds 7/8) -------
// Base program of 56 slots shared by all 4 k-groups g (sigma_g = XOR(4g) on dims,
// = XOR(2g) on pair index u). Lane group g holds the sigma_g-permuted h; running
// the SAME program yields the sigma_g-image term.
// Slots: 0-3 LIN(a=0..3), 4-7 SIN(a=0..3), 8-11 DIAG(a=0..3),
// 12-13 within-pair cross (h0h1, h2h3),
// 14-29 odd-distance pair reps {P0,Pv} v=1,3,5,7 (all groups live),
// 30-53 even-distance pair reps {0,2},{1,3},{0,4},{1,5},{0,6},{1,7} (half dead),
// 54-55 dead pad. ONE (row 0) folded into acc preload.
__host__ __device__ constexpr int quadrow(int x, int y) {
    if (x > y) { int t = x; x = y; y = t; }
    return 17 + x * 16 - x * (x - 1) / 2 + (y - x);     // np.triu_indices order
}

__host__ __device__ constexpr int krow16(int m, int g) {
    const int sh = 4 * g;
    if (m < 4)  return 1 + (m ^ sh);
    if (m < 8)  return 153 + ((m - 4) ^ sh);
    if (m < 12) { const int a = (m - 8) ^ sh; return quadrow(a, a); }
    if (m < 14) { const int u = m - 12; return quadrow((2*u) ^ sh, (2*u+1) ^ sh); }
    if (m < 30) {
        const int idx = m - 14, rep = idx >> 2, w = idx & 3;
        const int v = 2 * rep + 1;
        const int a = ((w == 1 || w == 3) ? 1 : 0);
        const int b = 2 * v + ((w == 1 || w == 2) ? 1 : 0);
        return quadrow(a ^ sh, b ^ sh);
    }
    if (m < 54) {
        const int idx = m - 30, rep = idx >> 2, w = idx & 3;
        const int u = rep & 1;
        const int v = 2 + 2 * (rep >> 1) + (rep & 1);
        const int d = u ^ v;
        const bool live = (d == 2) ? (g == 0 || g == 2) : (g == 0 || g == 1);
        if (!live) return -1;
        const int a = 2 * u + ((w == 1 || w == 3) ? 1 : 0);
        const int b = 2 * v + ((w == 1 || w == 2) ? 1 : 0);
        return quadrow(a ^ sh, b ^ sh);
    }
    return -1;
}

// ---------------- kernel 1: pack A fragments + c0 into ws (unchanged) --------
__global__ __launch_bounds__(448) void pack_A16_kernel(
    const float* __restrict__ coeff, const float* __restrict__ mask, char* __restrict__ ws)
{
    const int r = blockIdx.x;
    const int tid = threadIdx.x;          // 448 = 7 chunks x 64 lanes
    const int c = tid >> 6, lane = tid & 63;
    const int d = lane & 15, g = lane >> 4;
    const float* cr = coeff + (size_t)r * NTERMS * LATENT;
    const float* mr = mask  + (size_t)r * NTERMS * LATENT;
    FragHE a;
    for (int e = 0; e < 8; ++e) {
        const int row = krow16(c * 8 + e, g);
        float v = 0.0f;
        if (row >= 0) v = cr[row * LATENT + d] * mr[row * LATENT + d] * (DT * ASCALE);
        a.e[e] = (_Float16)v;
    }
    reinterpret_cast<int4v*>(ws)[((size_t)r * NCHUNK + c) * 64 + lane] = a.i4;

    if (tid < LATENT) {
        float* c0p = reinterpret_cast<float*>(ws + WS_C0_OFF);
        c0p[r * LATENT + tid] = cr[tid] * mr[tid] * (DT * ASCALE);   // library row 0
    }
}

// ---------------- kernel 2: main integration ----------------
// One wave = 16 trajectories x 4 k-groups. col=lane&15, g=lane>>4.
// Each lane keeps ONLY its own 4-dim block (global dims 4g..4g+3) in f32;
// the other 12 h-values circulate as packed f16 pairs via 6 shfl_xor/step.
// af/c0s are asm-pinned so the allocator cannot sink their loads into the loop.
template<bool USE_WS>
__global__ __launch_bounds__(256, 4) void sindy_f16_kernel(
    const float* __restrict__ h_t,    // [N, 16]
    const float* __restrict__ coeff,  // [10, 169, 16]
    const float* __restrict__ mask,   // [10, 169, 16]
    const char* __restrict__ ws,
    float* __restrict__ out,          // [N, 10, 16]
    int N, int ntiles)
{
    const int lane = threadIdx.x & 63;
    const int wid  = blockIdx.x * 4 + (threadIdx.x >> 6);
    if (wid >= NREP * ntiles) return;
    const int r    = wid / ntiles;
    const int tile = wid % ntiles;

    const int col = lane & 15;        // trajectory within tile; also A dim column
    const int g   = lane >> 4;        // k-group; sigma = XOR(4g)

    // ---- A fragments (28 VGPR, loop-invariant, PINNED resident) ----
    int4v afi[NCHUNK];
    if constexpr (USE_WS) {
        const int4v* wa = reinterpret_cast<const int4v*>(ws);
        #pragma unroll
        for (int c = 0; c < NCHUNK; ++c)
            afi[c] = wa[((size_t)r * NCHUNK + c) * 64 + lane];
    } else {
        const float* cr = coeff + (size_t)r * NTERMS * LATENT;
        const float* mr = mask  + (size_t)r * NTERMS * LATENT;
        #pragma unroll
        for (int c = 0; c < NCHUNK; ++c) {
            FragHE a;
            #pragma unroll
            for (int e = 0; e < 8; ++e) {
                const int row = krow16(c * 8 + e, g);
                float v = 0.0f;
                if (row >= 0) v = cr[row * LATENT + col] * mr[row * LATENT + col] * (DT * ASCALE);
                a.e[e] = (_Float16)v;
            }
            afi[c] = a.i4;
        }
    }

    // ---- scaled constant column (ONE term), own dims 4g..4g+3 ----
    float c0s[4];
    if constexpr (USE_WS) {
        const float4 v = *reinterpret_cast<const float4*>(
            ws + WS_C0_OFF + ((size_t)r * LATENT + 4 * g) * 4);
        c0s[0] = v.x; c0s[1] = v.y; c0s[2] = v.z; c0s[3] = v.w;
    } else {
        const float* cr = coeff + (size_t)r * NTERMS * LATENT;
        const float* mr = mask  + (size_t)r * NTERMS * LATENT;
        #pragma unroll
        for (int j = 0; j < 4; ++j) {
            const int d2 = 4 * g + j;
            c0s[j] = cr[d2] * mr[d2] * (DT * ASCALE);
        }
    }

    // Opaque-value barrier: values become asm results, so the compiler cannot
    // rematerialize/sink the loads into the step loop. One-time, zero instrs.
    #pragma unroll
    for (int c = 0; c < NCHUNK; ++c) asm volatile("" : "+v"(afi[c]));
    asm volatile("" : "+v"(c0s[0]), "+v"(c0s[1]), "+v"(c0s[2]), "+v"(c0s[3]));

    // ---- own h block only: h[j] = h_global[4g + j] (one float4) ----
    const int n = tile * 16 + col;
    float h0, h1, h2c, h3c;
    {
        float4 q = make_float4(0.f, 0.f, 0.f, 0.f);
        if (n < N)
            q = *reinterpret_cast<const float4*>(h_t + (size_t)n * LATENT + 4 * g);
        h0 = q.x; h1 = q.y; h2c = q.z; h3c = q.w;
    }

    // ---- 10 sequential Euler steps ----
    for (int s = 0; s < NSTEPS; ++s) {
        // own pairs, then broadcast packed pairs across g-groups:
        // hp[2u+t] = pair t of sigma_g-permuted block u  (= own pair of group g^u)
        h2 hp[8];
        hp[0] = pkrtz(h0, h1);
        hp[1] = pkrtz(h2c, h3c);
        #pragma unroll
        for (int u = 1; u < 4; ++u) {
            hp[2 * u]     = shfl_xor_h2(hp[0], 16 * u);
            hp[2 * u + 1] = shfl_xor_h2(hp[1], 16 * u);
        }

        // preload: acc = 1024*h_old + 1024*c0 -> acc_post = 1024*h_new
        f32x4 acc;
        acc[0] = fmaf(h0,  ASCALE, c0s[0]);
        acc[1] = fmaf(h1,  ASCALE, c0s[1]);
        acc[2] = fmaf(h2c, ASCALE, c0s[2]);
        acc[3] = fmaf(h3c, ASCALE, c0s[3]);

        FragH f;
        #define MM(C) acc = __builtin_amdgcn_mfma_f32_16x16x32_f16( \
            __builtin_bit_cast(half8, afi[C]), f.v, acc, 0, 0, 0);
        // c0: lin 0-3, sin 0-3 (own block f32)
        f.p[0] = hp[0]; f.p[1] = hp[1];
        f.p[2] = pkrtz(__sinf(h0), __sinf(h1));
        f.p[3] = pkrtz(__sinf(h2c), __sinf(h3c));
        MM(0)
        // c1: diag 0-3, within-pair crosses (own f32), odd-rep v=1 pkA
        f.p[0] = hp[0] * hp[0]; f.p[1] = hp[1] * hp[1];
        f.p[2] = pkrtz(h0 * h1, h2c * h3c);
        f.p[3] = hp[0] * hp[1];
        MM(1)
        // c2
        f.p[0] = hp[0] * SW(hp[1]); f.p[1] = hp[0] * hp[3];
        f.p[2] = hp[0] * SW(hp[3]); f.p[3] = hp[0] * hp[5];
        MM(2)
        // c3
        f.p[0] = hp[0] * SW(hp[5]); f.p[1] = hp[0] * hp[7];
        f.p[2] = hp[0] * SW(hp[7]); f.p[3] = hp[0] * hp[2];
        MM(3)
        // c4
        f.p[0] = hp[0] * SW(hp[2]); f.p[1] = hp[1] * hp[3];
        f.p[2] = hp[1] * SW(hp[3]); f.p[3] = hp[0] * hp[4];
        MM(4)
        // c5
        f.p[0] = hp[0] * SW(hp[4]); f.p[1] = hp[1] * hp[5];
        f.p[2] = hp[1] * SW(hp[5]); f.p[3] = hp[0] * hp[6];
        MM(5)
        // c6
        f.p[0] = hp[0] * SW(hp[6]); f.p[1] = hp[1] * hp[7];
        f.p[2] = hp[1] * SW(hp[7]); f.p[3] = (h2)(_Float16)0;
        MM(6)
        #undef MM

        // scale back (exact pow2): new own h
        h0  = acc[0] * INV_ASCALE;
        h1  = acc[1] * INV_ASCALE;
        h2c = acc[2] * INV_ASCALE;
        h3c = acc[3] * INV_ASCALE;
    }

    // ---- store: out[n][r][4g+j] = own h ----
    if (n < N) {
        float* op = out + ((size_t)n * NREP + r) * LATENT + 4 * g;
        *reinterpret_cast<float4*>(op) = make_float4(h0, h1, h2c, h3c);
    }
}

extern "C" void kernel_launch(void* const* d_in, const int* in_sizes, int n_in,
                              void* d_out, int out_size, void* d_ws, size_t ws_size,
                              hipStream_t stream) {
    const float* h_t   = (const float*)d_in[0];
    const float* coeff = (const float*)d_in[1];
    const float* mask  = (const float*)d_in[2];
    float* out = (float*)d_out;

    const int N = in_sizes[0] / LATENT;          // 50000
    const int ntiles = (N + 15) / 16;            // 3125
    const int nwaves = NREP * ntiles;            // 31250
    const int nblocks = (nwaves + 3) / 4;

    if (ws_size >= (size_t)WS_TOTAL) {
        pack_A16_kernel<<<dim3(NREP), dim3(448), 0, stream>>>(coeff, mask, (char*)d_ws);
        sindy_f16_kernel<true><<<dim3(nblocks), dim3(256), 0, stream>>>(
            h_t, coeff, mask, (const char*)d_ws, out, N, ntiles);
    } else {
        sindy_f16_kernel<false><<<dim3(nblocks), dim3(256), 0, stream>>>(
            h_t, coeff, mask, (const char*)d_ws, out, N, ntiles);
    }
}

// Round 10
// 55.181 us; speedup vs baseline: 1.0056x; 1.0056x over previous
//
#include <hip/hip_runtime.h>
#include <hip/hip_bf16.h>
#include <math.h>

#define LATENT 16
#define NREP 10
#define NSTEPS 10
#define NTERMS 169          // 1 + 16 + 136 + 16
#define NCHUNK 7            // 7 x K=32 = 224 k-slots (168 live + dead pads; ONE folded)
#define DT 0.01f
#define ASCALE 1024.0f      // exact pow2: lifts f16 A-coeffs out of subnormal range
#define INV_ASCALE (1.0f/1024.0f)

#define WS_A_BYTES (NREP * NCHUNK * 64 * 16)     // 71680
#define WS_C0_OFF  WS_A_BYTES
#define WS_TOTAL   (WS_A_BYTES + NREP * LATENT * 4)

typedef _Float16 h2 __attribute__((ext_vector_type(2)));
typedef _Float16 half8 __attribute__((ext_vector_type(8)));
typedef __fp16 fp16x2 __attribute__((ext_vector_type(2)));
typedef __attribute__((ext_vector_type(4))) float f32x4;
typedef int int4v __attribute__((ext_vector_type(4)));

union FragH  { half8 v; h2 p[4]; int4v i4; };
union FragHE { half8 v; _Float16 e[8]; int4v i4; };

#define SW(x) __builtin_shufflevector((x), (x), 1, 0)

__device__ __forceinline__ h2 pkrtz(float a, float b) {
    fp16x2 r = __builtin_amdgcn_cvt_pkrtz(a, b);
    return __builtin_bit_cast(h2, r);
}

__device__ __forceinline__ h2 shfl_xor_h2(h2 v, int mask) {
    int i = __builtin_bit_cast(int, v);
    return __builtin_bit_cast(h2, __shfl_xor(i, mask));
}

// ---------------- slot -> library row mapping (IDENTICAL to rounds 7/8/9) -----
// Base program of 56 slots shared by all 4 k-groups g (sigma_g = XOR(4g) on dims,
// = XOR(2g) on pair index u). Lane group g holds the sigma_g-permuted h; running
// the SAME program yields the sigma_g-image term.
// Slots: 0-3 LIN(a=0..3), 4-7 SIN(a=0..3), 8-11 DIAG(a=0..3),
// 12-13 within-pair cross (h0h1, h2h3),
// 14-29 odd-distance pair reps {P0,Pv} v=1,3,5,7 (all groups live),
// 30-53 even-distance pair reps {0,2},{1,3},{0,4},{1,5},{0,6},{1,7} (half dead),
// 54-55 dead pad. ONE (row 0) folded into acc preload.
__host__ __device__ constexpr int quadrow(int x, int y) {
    if (x > y) { int t = x; x = y; y = t; }
    return 17 + x * 16 - x * (x - 1) / 2 + (y - x);     // np.triu_indices order
}

__host__ __device__ constexpr int krow16(int m, int g) {
    const int sh = 4 * g;
    if (m < 4)  return 1 + (m ^ sh);
    if (m < 8)  return 153 + ((m - 4) ^ sh);
    if (m < 12) { const int a = (m - 8) ^ sh; return quadrow(a, a); }
    if (m < 14) { const int u = m - 12; return quadrow((2*u) ^ sh, (2*u+1) ^ sh); }
    if (m < 30) {
        const int idx = m - 14, rep = idx >> 2, w = idx & 3;
        const int v = 2 * rep + 1;
        const int a = ((w == 1 || w == 3) ? 1 : 0);
        const int b = 2 * v + ((w == 1 || w == 2) ? 1 : 0);
        return quadrow(a ^ sh, b ^ sh);
    }
    if (m < 54) {
        const int idx = m - 30, rep = idx >> 2, w = idx & 3;
        const int u = rep & 1;
        const int v = 2 + 2 * (rep >> 1) + (rep & 1);
        const int d = u ^ v;
        const bool live = (d == 2) ? (g == 0 || g == 2) : (g == 0 || g == 1);
        if (!live) return -1;
        const int a = 2 * u + ((w == 1 || w == 3) ? 1 : 0);
        const int b = 2 * v + ((w == 1 || w == 2) ? 1 : 0);
        return quadrow(a ^ sh, b ^ sh);
    }
    return -1;
}

// ---------------- per-chunk B-fragment builder (g-uniform) ----------------
template<int C>
__device__ __forceinline__ half8 buildf(const float (&hq)[4], const h2 (&hp)[8]) {
    FragH f;
    if constexpr (C == 0) {
        f.p[0] = hp[0]; f.p[1] = hp[1];
        f.p[2] = pkrtz(__sinf(hq[0]), __sinf(hq[1]));
        f.p[3] = pkrtz(__sinf(hq[2]), __sinf(hq[3]));
    } else if constexpr (C == 1) {
        f.p[0] = hp[0] * hp[0]; f.p[1] = hp[1] * hp[1];
        f.p[2] = pkrtz(hq[0] * hq[1], hq[2] * hq[3]);
        f.p[3] = hp[0] * hp[1];
    } else if constexpr (C == 2) {
        f.p[0] = hp[0] * SW(hp[1]); f.p[1] = hp[0] * hp[3];
        f.p[2] = hp[0] * SW(hp[3]); f.p[3] = hp[0] * hp[5];
    } else if constexpr (C == 3) {
        f.p[0] = hp[0] * SW(hp[5]); f.p[1] = hp[0] * hp[7];
        f.p[2] = hp[0] * SW(hp[7]); f.p[3] = hp[0] * hp[2];
    } else if constexpr (C == 4) {
        f.p[0] = hp[0] * SW(hp[2]); f.p[1] = hp[1] * hp[3];
        f.p[2] = hp[1] * SW(hp[3]); f.p[3] = hp[0] * hp[4];
    } else if constexpr (C == 5) {
        f.p[0] = hp[0] * SW(hp[4]); f.p[1] = hp[1] * hp[5];
        f.p[2] = hp[1] * SW(hp[5]); f.p[3] = hp[0] * hp[6];
    } else {
        f.p[0] = hp[0] * SW(hp[6]); f.p[1] = hp[1] * hp[7];
        f.p[2] = hp[1] * SW(hp[7]); f.p[3] = (h2)(_Float16)0;
    }
    return f.v;
}

// ---------------- kernel 1: pack A fragments + c0 into ws --------------------
// 70 blocks x 64 threads: blockIdx = r*NCHUNK + c.
__global__ __launch_bounds__(64) void pack_A16_kernel(
    const float* __restrict__ coeff, const float* __restrict__ mask, char* __restrict__ ws)
{
    const int r = blockIdx.x / NCHUNK;
    const int c = blockIdx.x % NCHUNK;
    const int lane = threadIdx.x;
    const int d = lane & 15, g = lane >> 4;
    const float* cr = coeff + (size_t)r * NTERMS * LATENT;
    const float* mr = mask  + (size_t)r * NTERMS * LATENT;
    FragHE a;
    for (int e = 0; e < 8; ++e) {
        const int row = krow16(c * 8 + e, g);
        float v = 0.0f;
        if (row >= 0) v = cr[row * LATENT + d] * mr[row * LATENT + d] * (DT * ASCALE);
        a.e[e] = (_Float16)v;
    }
    reinterpret_cast<int4v*>(ws)[((size_t)r * NCHUNK + c) * 64 + lane] = a.i4;

    if (c == 0 && lane < LATENT) {
        float* c0p = reinterpret_cast<float*>(ws + WS_C0_OFF);
        c0p[r * LATENT + lane] = cr[lane] * mr[lane] * (DT * ASCALE);   // row 0
    }
}

// ---------------- kernel 2: main integration, DUAL-TILE per wave -------------
// One wave = 2 independent 16-trajectory tiles x 4 k-groups, sharing af/c0s.
// Two independent MFMA/VALU dep chains interleaved -> fills issue/latency gaps.
template<bool USE_WS>
__global__ __launch_bounds__(256, 3) void sindy_f16_kernel(
    const float* __restrict__ h_t,    // [N, 16]
    const float* __restrict__ coeff,  // [10, 169, 16]
    const float* __restrict__ mask,   // [10, 169, 16]
    const char* __restrict__ ws,
    float* __restrict__ out,          // [N, 10, 16]
    int N, int npairs)
{
    const int lane = threadIdx.x & 63;
    const int wid  = blockIdx.x * 4 + (threadIdx.x >> 6);
    if (wid >= NREP * npairs) return;
    const int r    = wid / npairs;
    const int pair = wid % npairs;

    const int col = lane & 15;        // trajectory within tile; also A dim column
    const int g   = lane >> 4;        // k-group; sigma = XOR(4g)

    // ---- A fragments (shared by both tiles, loop-invariant) ----
    int4v afi[NCHUNK];
    if constexpr (USE_WS) {
        const int4v* wa = reinterpret_cast<const int4v*>(ws);
        #pragma unroll
        for (int c = 0; c < NCHUNK; ++c)
            afi[c] = wa[((size_t)r * NCHUNK + c) * 64 + lane];
    } else {
        const float* cr = coeff + (size_t)r * NTERMS * LATENT;
        const float* mr = mask  + (size_t)r * NTERMS * LATENT;
        #pragma unroll
        for (int c = 0; c < NCHUNK; ++c) {
            FragHE a;
            #pragma unroll
            for (int e = 0; e < 8; ++e) {
                const int row = krow16(c * 8 + e, g);
                float v = 0.0f;
                if (row >= 0) v = cr[row * LATENT + col] * mr[row * LATENT + col] * (DT * ASCALE);
                a.e[e] = (_Float16)v;
            }
            afi[c] = a.i4;
        }
    }

    // ---- scaled constant column (ONE term), own dims 4g..4g+3 ----
    float c0s[4];
    if constexpr (USE_WS) {
        const float4 v = *reinterpret_cast<const float4*>(
            ws + WS_C0_OFF + ((size_t)r * LATENT + 4 * g) * 4);
        c0s[0] = v.x; c0s[1] = v.y; c0s[2] = v.z; c0s[3] = v.w;
    } else {
        const float* cr = coeff + (size_t)r * NTERMS * LATENT;
        const float* mr = mask  + (size_t)r * NTERMS * LATENT;
        #pragma unroll
        for (int j = 0; j < 4; ++j) {
            const int d2 = 4 * g + j;
            c0s[j] = cr[d2] * mr[d2] * (DT * ASCALE);
        }
    }

    // ---- own h blocks for both tiles (global dims 4g..4g+3) ----
    const int nA = (2 * pair) * 16 + col;
    const int nB = nA + 16;
    float hqA[4], hqB[4];
    {
        float4 q = make_float4(0.f, 0.f, 0.f, 0.f);
        if (nA < N) q = *reinterpret_cast<const float4*>(h_t + (size_t)nA * LATENT + 4 * g);
        hqA[0] = q.x; hqA[1] = q.y; hqA[2] = q.z; hqA[3] = q.w;
        float4 p = make_float4(0.f, 0.f, 0.f, 0.f);
        if (nB < N) p = *reinterpret_cast<const float4*>(h_t + (size_t)nB * LATENT + 4 * g);
        hqB[0] = p.x; hqB[1] = p.y; hqB[2] = p.z; hqB[3] = p.w;
    }

    // ---- 10 sequential Euler steps, two independent chains ----
    for (int s = 0; s < NSTEPS; ++s) {
        h2 hpA[8], hpB[8];
        hpA[0] = pkrtz(hqA[0], hqA[1]); hpA[1] = pkrtz(hqA[2], hqA[3]);
        hpB[0] = pkrtz(hqB[0], hqB[1]); hpB[1] = pkrtz(hqB[2], hqB[3]);
        #pragma unroll
        for (int u = 1; u < 4; ++u) {
            hpA[2 * u]     = shfl_xor_h2(hpA[0], 16 * u);
            hpA[2 * u + 1] = shfl_xor_h2(hpA[1], 16 * u);
            hpB[2 * u]     = shfl_xor_h2(hpB[0], 16 * u);
            hpB[2 * u + 1] = shfl_xor_h2(hpB[1], 16 * u);
        }

        f32x4 accA, accB;
        accA[0] = fmaf(hqA[0], ASCALE, c0s[0]);
        accA[1] = fmaf(hqA[1], ASCALE, c0s[1]);
        accA[2] = fmaf(hqA[2], ASCALE, c0s[2]);
        accA[3] = fmaf(hqA[3], ASCALE, c0s[3]);
        accB[0] = fmaf(hqB[0], ASCALE, c0s[0]);
        accB[1] = fmaf(hqB[1], ASCALE, c0s[1]);
        accB[2] = fmaf(hqB[2], ASCALE, c0s[2]);
        accB[3] = fmaf(hqB[3], ASCALE, c0s[3]);

        #define MMPAIR(C) \
            accA = __builtin_amdgcn_mfma_f32_16x16x32_f16( \
                __builtin_bit_cast(half8, afi[C]), buildf<C>(hqA, hpA), accA, 0, 0, 0); \
            accB = __builtin_amdgcn_mfma_f32_16x16x32_f16( \
                __builtin_bit_cast(half8, afi[C]), buildf<C>(hqB, hpB), accB, 0, 0, 0);
        MMPAIR(0) MMPAIR(1) MMPAIR(2) MMPAIR(3) MMPAIR(4) MMPAIR(5) MMPAIR(6)
        #undef MMPAIR

        hqA[0] = accA[0] * INV_ASCALE; hqA[1] = accA[1] * INV_ASCALE;
        hqA[2] = accA[2] * INV_ASCALE; hqA[3] = accA[3] * INV_ASCALE;
        hqB[0] = accB[0] * INV_ASCALE; hqB[1] = accB[1] * INV_ASCALE;
        hqB[2] = accB[2] * INV_ASCALE; hqB[3] = accB[3] * INV_ASCALE;
    }

    // ---- store: out[n][r][4g+j] ----
    if (nA < N) {
        float* op = out + ((size_t)nA * NREP + r) * LATENT + 4 * g;
        *reinterpret_cast<float4*>(op) = make_float4(hqA[0], hqA[1], hqA[2], hqA[3]);
    }
    if (nB < N) {
        float* op = out + ((size_t)nB * NREP + r) * LATENT + 4 * g;
        *reinterpret_cast<float4*>(op) = make_float4(hqB[0], hqB[1], hqB[2], hqB[3]);
    }
}

extern "C" void kernel_launch(void* const* d_in, const int* in_sizes, int n_in,
                              void* d_out, int out_size, void* d_ws, size_t ws_size,
                              hipStream_t stream) {
    const float* h_t   = (const float*)d_in[0];
    const float* coeff = (const float*)d_in[1];
    const float* mask  = (const float*)d_in[2];
    float* out = (float*)d_out;

    const int N = in_sizes[0] / LATENT;          // 50000
    const int ntiles = (N + 15) / 16;            // 3125
    const int npairs = (ntiles + 1) / 2;         // 1563
    const int nwaves = NREP * npairs;            // 15630
    const int nblocks = (nwaves + 3) / 4;

    if (ws_size >= (size_t)WS_TOTAL) {
        pack_A16_kernel<<<dim3(NREP * NCHUNK), dim3(64), 0, stream>>>(coeff, mask, (char*)d_ws);
        sindy_f16_kernel<true><<<dim3(nblocks), dim3(256), 0, stream>>>(
            h_t, coeff, mask, (const char*)d_ws, out, N, npairs);
    } else {
        sindy_f16_kernel<false><<<dim3(nblocks), dim3(256), 0, stream>>>(
            h_t, coeff, mask, (const char*)d_ws, out, N, npairs);
    }
}

// Round 11
// 54.602 us; speedup vs baseline: 1.0163x; 1.0106x over previous
//
#include <hip/hip_runtime.h>
#include <hip/hip_bf16.h>
#include <math.h>

#define LATENT 16
#define NREP 10
#define NSTEPS 10
#define NTERMS 169          // 1 + 16 + 136 + 16
#define NCHUNK 7            // 7 x K=32 = 224 k-slots (168 live + dead pads; ONE folded)
#define DT 0.01f
#define ASCALE 1024.0f      // exact pow2: lifts f16 A-coeffs out of subnormal range
#define INV_ASCALE (1.0f/1024.0f)

#define WS_A_BYTES (NREP * NCHUNK * 64 * 16)     // 71680
#define WS_C0_OFF  WS_A_BYTES
#define WS_TOTAL   (WS_A_BYTES + NREP * LATENT * 4)

typedef _Float16 h2 __attribute__((ext_vector_type(2)));
typedef _Float16 half8 __attribute__((ext_vector_type(8)));
typedef __fp16 fp16x2 __attribute__((ext_vector_type(2)));
typedef __attribute__((ext_vector_type(4))) float f32x4;
typedef int int4v __attribute__((ext_vector_type(4)));

union FragH  { half8 v; h2 p[4]; int4v i4; };
union FragHE { half8 v; _Float16 e[8]; int4v i4; };

#define SW(x) __builtin_shufflevector((x), (x), 1, 0)

__device__ __forceinline__ h2 pkrtz(float a, float b) {
    fp16x2 r = __builtin_amdgcn_cvt_pkrtz(a, b);
    return __builtin_bit_cast(h2, r);
}

__device__ __forceinline__ h2 shfl_xor_h2(h2 v, int mask) {
    int i = __builtin_bit_cast(int, v);
    return __builtin_bit_cast(h2, __shfl_xor(i, mask));
}

// Inline-asm MFMA: all operands pinned to ARCH VGPRs ("v") so the allocator
// cannot park A/acc in AGPRs and shuttle via v_accvgpr_read/write per use.
// s_nop 1 covers the VALU-write -> MFMA-read (SrcA/B/C) hazard (2 states);
// the asm is opaque to the compiler's MAI hazard recognizer, so we do it here.
__device__ __forceinline__ void mfma16(f32x4& acc, const int4v a, const int4v b) {
    asm("s_nop 1\n\tv_mfma_f32_16x16x32_f16 %0, %1, %2, %0"
        : "+v"(acc) : "v"(a), "v"(b));
}

// ---------------- slot -> library row mapping (IDENTICAL to rounds 7-10) ------
// Base program of 56 slots shared by all 4 k-groups g (sigma_g = XOR(4g) on dims,
// = XOR(2g) on pair index u). Lane group g holds the sigma_g-permuted h; running
// the SAME program yields the sigma_g-image term.
// Slots: 0-3 LIN(a=0..3), 4-7 SIN(a=0..3), 8-11 DIAG(a=0..3),
// 12-13 within-pair cross (h0h1, h2h3),
// 14-29 odd-distance pair reps {P0,Pv} v=1,3,5,7 (all groups live),
// 30-53 even-distance pair reps {0,2},{1,3},{0,4},{1,5},{0,6},{1,7} (half dead),
// 54-55 dead pad. ONE (row 0) folded into acc preload.
__host__ __device__ constexpr int quadrow(int x, int y) {
    if (x > y) { int t = x; x = y; y = t; }
    return 17 + x * 16 - x * (x - 1) / 2 + (y - x);     // np.triu_indices order
}

__host__ __device__ constexpr int krow16(int m, int g) {
    const int sh = 4 * g;
    if (m < 4)  return 1 + (m ^ sh);
    if (m < 8)  return 153 + ((m - 4) ^ sh);
    if (m < 12) { const int a = (m - 8) ^ sh; return quadrow(a, a); }
    if (m < 14) { const int u = m - 12; return quadrow((2*u) ^ sh, (2*u+1) ^ sh); }
    if (m < 30) {
        const int idx = m - 14, rep = idx >> 2, w = idx & 3;
        const int v = 2 * rep + 1;
        const int a = ((w == 1 || w == 3) ? 1 : 0);
        const int b = 2 * v + ((w == 1 || w == 2) ? 1 : 0);
        return quadrow(a ^ sh, b ^ sh);
    }
    if (m < 54) {
        const int idx = m - 30, rep = idx >> 2, w = idx & 3;
        const int u = rep & 1;
        const int v = 2 + 2 * (rep >> 1) + (rep & 1);
        const int d = u ^ v;
        const bool live = (d == 2) ? (g == 0 || g == 2) : (g == 0 || g == 1);
        if (!live) return -1;
        const int a = 2 * u + ((w == 1 || w == 3) ? 1 : 0);
        const int b = 2 * v + ((w == 1 || w == 2) ? 1 : 0);
        return quadrow(a ^ sh, b ^ sh);
    }
    return -1;
}

// ---------------- per-chunk B-fragment builder (g-uniform) ----------------
template<int C>
__device__ __forceinline__ int4v buildf(const float (&hq)[4], const h2 (&hp)[8]) {
    FragH f;
    if constexpr (C == 0) {
        f.p[0] = hp[0]; f.p[1] = hp[1];
        f.p[2] = pkrtz(__sinf(hq[0]), __sinf(hq[1]));
        f.p[3] = pkrtz(__sinf(hq[2]), __sinf(hq[3]));
    } else if constexpr (C == 1) {
        f.p[0] = hp[0] * hp[0]; f.p[1] = hp[1] * hp[1];
        f.p[2] = pkrtz(hq[0] * hq[1], hq[2] * hq[3]);
        f.p[3] = hp[0] * hp[1];
    } else if constexpr (C == 2) {
        f.p[0] = hp[0] * SW(hp[1]); f.p[1] = hp[0] * hp[3];
        f.p[2] = hp[0] * SW(hp[3]); f.p[3] = hp[0] * hp[5];
    } else if constexpr (C == 3) {
        f.p[0] = hp[0] * SW(hp[5]); f.p[1] = hp[0] * hp[7];
        f.p[2] = hp[0] * SW(hp[7]); f.p[3] = hp[0] * hp[2];
    } else if constexpr (C == 4) {
        f.p[0] = hp[0] * SW(hp[2]); f.p[1] = hp[1] * hp[3];
        f.p[2] = hp[1] * SW(hp[3]); f.p[3] = hp[0] * hp[4];
    } else if constexpr (C == 5) {
        f.p[0] = hp[0] * SW(hp[4]); f.p[1] = hp[1] * hp[5];
        f.p[2] = hp[1] * SW(hp[5]); f.p[3] = hp[0] * hp[6];
    } else {
        f.p[0] = hp[0] * SW(hp[6]); f.p[1] = hp[1] * hp[7];
        f.p[2] = hp[1] * SW(hp[7]); f.p[3] = (h2)(_Float16)0;
    }
    return f.i4;
}

// ---------------- kernel 1: pack A fragments + c0 into ws --------------------
// 70 blocks x 64 threads: blockIdx = r*NCHUNK + c.
__global__ __launch_bounds__(64) void pack_A16_kernel(
    const float* __restrict__ coeff, const float* __restrict__ mask, char* __restrict__ ws)
{
    const int r = blockIdx.x / NCHUNK;
    const int c = blockIdx.x % NCHUNK;
    const int lane = threadIdx.x;
    const int d = lane & 15, g = lane >> 4;
    const float* cr = coeff + (size_t)r * NTERMS * LATENT;
    const float* mr = mask  + (size_t)r * NTERMS * LATENT;
    FragHE a;
    for (int e = 0; e < 8; ++e) {
        const int row = krow16(c * 8 + e, g);
        float v = 0.0f;
        if (row >= 0) v = cr[row * LATENT + d] * mr[row * LATENT + d] * (DT * ASCALE);
        a.e[e] = (_Float16)v;
    }
    reinterpret_cast<int4v*>(ws)[((size_t)r * NCHUNK + c) * 64 + lane] = a.i4;

    if (c == 0 && lane < LATENT) {
        float* c0p = reinterpret_cast<float*>(ws + WS_C0_OFF);
        c0p[r * LATENT + lane] = cr[lane] * mr[lane] * (DT * ASCALE);   // row 0
    }
}

// ---------------- kernel 2: main integration (single tile, asm MFMA) ---------
// One wave = 16 trajectories x 4 k-groups. col=lane&15, g=lane>>4.
// Each lane keeps ONLY its own 4-dim block (global dims 4g..4g+3) in f32;
// the other 12 h-values circulate as packed f16 pairs via 6 shfl_xor/step.
template<bool USE_WS>
__global__ __launch_bounds__(256, 4) void sindy_f16_kernel(
    const float* __restrict__ h_t,    // [N, 16]
    const float* __restrict__ coeff,  // [10, 169, 16]
    const float* __restrict__ mask,   // [10, 169, 16]
    const char* __restrict__ ws,
    float* __restrict__ out,          // [N, 10, 16]
    int N, int ntiles)
{
    const int lane = threadIdx.x & 63;
    const int wid  = blockIdx.x * 4 + (threadIdx.x >> 6);
    if (wid >= NREP * ntiles) return;
    const int r    = wid / ntiles;
    const int tile = wid % ntiles;

    const int col = lane & 15;        // trajectory within tile; also A dim column
    const int g   = lane >> 4;        // k-group; sigma = XOR(4g)

    // ---- A fragments (28 VGPR, loop-invariant) ----
    int4v afi[NCHUNK];
    if constexpr (USE_WS) {
        const int4v* wa = reinterpret_cast<const int4v*>(ws);
        #pragma unroll
        for (int c = 0; c < NCHUNK; ++c)
            afi[c] = wa[((size_t)r * NCHUNK + c) * 64 + lane];
    } else {
        const float* cr = coeff + (size_t)r * NTERMS * LATENT;
        const float* mr = mask  + (size_t)r * NTERMS * LATENT;
        #pragma unroll
        for (int c = 0; c < NCHUNK; ++c) {
            FragHE a;
            #pragma unroll
            for (int e = 0; e < 8; ++e) {
                const int row = krow16(c * 8 + e, g);
                float v = 0.0f;
                if (row >= 0) v = cr[row * LATENT + col] * mr[row * LATENT + col] * (DT * ASCALE);
                a.e[e] = (_Float16)v;
            }
            afi[c] = a.i4;
        }
    }

    // ---- scaled constant column (ONE term), own dims 4g..4g+3 ----
    float c0s[4];
    if constexpr (USE_WS) {
        const float4 v = *reinterpret_cast<const float4*>(
            ws + WS_C0_OFF + ((size_t)r * LATENT + 4 * g) * 4);
        c0s[0] = v.x; c0s[1] = v.y; c0s[2] = v.z; c0s[3] = v.w;
    } else {
        const float* cr = coeff + (size_t)r * NTERMS * LATENT;
        const float* mr = mask  + (size_t)r * NTERMS * LATENT;
        #pragma unroll
        for (int j = 0; j < 4; ++j) {
            const int d2 = 4 * g + j;
            c0s[j] = cr[d2] * mr[d2] * (DT * ASCALE);
        }
    }

    // ---- own h block only: h[j] = h_global[4g + j] (one float4) ----
    const int n = tile * 16 + col;
    float hq[4];
    {
        float4 q = make_float4(0.f, 0.f, 0.f, 0.f);
        if (n < N)
            q = *reinterpret_cast<const float4*>(h_t + (size_t)n * LATENT + 4 * g);
        hq[0] = q.x; hq[1] = q.y; hq[2] = q.z; hq[3] = q.w;
    }

    // ---- 10 sequential Euler steps ----
    for (int s = 0; s < NSTEPS; ++s) {
        // own pairs, then broadcast packed pairs across g-groups:
        // hp[2u+t] = pair t of sigma_g-permuted block u  (= own pair of group g^u)
        h2 hp[8];
        hp[0] = pkrtz(hq[0], hq[1]);
        hp[1] = pkrtz(hq[2], hq[3]);
        #pragma unroll
        for (int u = 1; u < 4; ++u) {
            hp[2 * u]     = shfl_xor_h2(hp[0], 16 * u);
            hp[2 * u + 1] = shfl_xor_h2(hp[1], 16 * u);
        }

        // preload: acc = 1024*h_old + 1024*c0 -> acc_post = 1024*h_new
        f32x4 acc;
        acc[0] = fmaf(hq[0], ASCALE, c0s[0]);
        acc[1] = fmaf(hq[1], ASCALE, c0s[1]);
        acc[2] = fmaf(hq[2], ASCALE, c0s[2]);
        acc[3] = fmaf(hq[3], ASCALE, c0s[3]);

        mfma16(acc, afi[0], buildf<0>(hq, hp));
        mfma16(acc, afi[1], buildf<1>(hq, hp));
        mfma16(acc, afi[2], buildf<2>(hq, hp));
        mfma16(acc, afi[3], buildf<3>(hq, hp));
        mfma16(acc, afi[4], buildf<4>(hq, hp));
        mfma16(acc, afi[5], buildf<5>(hq, hp));
        mfma16(acc, afi[6], buildf<6>(hq, hp));

        // MFMA-dest -> VALU-read hazard drain (asm is opaque to the hazard
        // recognizer; ~4-pass MFMA needs ~7 states; 12 to be safe)
        asm volatile("s_nop 7\n\ts_nop 3" ::);

        // scale back (exact pow2): new own h
        hq[0] = acc[0] * INV_ASCALE;
        hq[1] = acc[1] * INV_ASCALE;
        hq[2] = acc[2] * INV_ASCALE;
        hq[3] = acc[3] * INV_ASCALE;
    }

    // ---- store: out[n][r][4g+j] = own h ----
    if (n < N) {
        float* op = out + ((size_t)n * NREP + r) * LATENT + 4 * g;
        *reinterpret_cast<float4*>(op) = make_float4(hq[0], hq[1], hq[2], hq[3]);
    }
}

extern "C" void kernel_launch(void* const* d_in, const int* in_sizes, int n_in,
                              void* d_out, int out_size, void* d_ws, size_t ws_size,
                              hipStream_t stream) {
    const float* h_t   = (const float*)d_in[0];
    const float* coeff = (const float*)d_in[1];
    const float* mask  = (const float*)d_in[2];
    float* out = (float*)d_out;

    const int N = in_sizes[0] / LATENT;          // 50000
    const int ntiles = (N + 15) / 16;            // 3125
    const int nwaves = NREP * ntiles;            // 31250
    const int nblocks = (nwaves + 3) / 4;

    if (ws_size >= (size_t)WS_TOTAL) {
        pack_A16_kernel<<<dim3(NREP * NCHUNK), dim3(64), 0, stream>>>(coeff, mask, (char*)d_ws);
        sindy_f16_kernel<true><<<dim3(nblocks), dim3(256), 0, stream>>>(
            h_t, coeff, mask, (const char*)d_ws, out, N, ntiles);
    } else {
        sindy_f16_kernel<false><<<dim3(nblocks), dim3(256), 0, stream>>>(
            h_t, coeff, mask, (const char*)d_ws, out, N, ntiles);
    }
}

// Round 12
// 54.139 us; speedup vs baseline: 1.0250x; 1.0086x over previous
//
#include <hip/hip_runtime.h>
#include <hip/hip_bf16.h>
#include <math.h>

#define LATENT 16
#define NREP 10
#define NSTEPS 10
#define NTERMS 169          // 1 + 16 + 136 + 16
#define NCHUNK 7            // 7 x K=32 = 224 k-slots (168 live + dead pads; ONE folded)
#define DT 0.01f
#define ASCALE 1024.0f      // exact pow2: lifts f16 A-coeffs out of subnormal range
#define INV_ASCALE (1.0f/1024.0f)

#define WS_A_BYTES (NREP * NCHUNK * 64 * 16)     // 71680
#define WS_C0_OFF  WS_A_BYTES
#define WS_TOTAL   (WS_A_BYTES + NREP * LATENT * 4)

typedef _Float16 h2 __attribute__((ext_vector_type(2)));
typedef _Float16 half8 __attribute__((ext_vector_type(8)));
typedef __fp16 fp16x2 __attribute__((ext_vector_type(2)));
typedef __attribute__((ext_vector_type(4))) float f32x4;
typedef int int4v __attribute__((ext_vector_type(4)));

union FragH  { half8 v; h2 p[4]; int4v i4; };
union FragHE { half8 v; _Float16 e[8]; int4v i4; };

#define SW(x) __builtin_shufflevector((x), (x), 1, 0)

__device__ __forceinline__ h2 pkrtz(float a, float b) {
    fp16x2 r = __builtin_amdgcn_cvt_pkrtz(a, b);
    return __builtin_bit_cast(h2, r);
}

// xor-broadcast via ds_bpermute with PRECOMPUTED byte index (no per-step VALU)
__device__ __forceinline__ h2 bperm_h2(int idx, h2 v) {
    return __builtin_bit_cast(h2,
        __builtin_amdgcn_ds_bpermute(idx, __builtin_bit_cast(int, v)));
}

// ---------------- slot -> library row mapping (IDENTICAL to rounds 7-11) ------
// Base program of 56 slots shared by all 4 k-groups g (sigma_g = XOR(4g) on dims,
// = XOR(2g) on pair index u). Lane group g holds the sigma_g-permuted h; running
// the SAME program yields the sigma_g-image term.
// Slots: 0-3 LIN(a=0..3), 4-7 SIN(a=0..3), 8-11 DIAG(a=0..3),
// 12-13 within-pair cross (h0h1, h2h3),
// 14-29 odd-distance pair reps {P0,Pv} v=1,3,5,7 (all groups live),
// 30-53 even-distance pair reps {0,2},{1,3},{0,4},{1,5},{0,6},{1,7} (half dead),
// 54-55 dead pad. ONE (row 0) folded into acc preload.
__host__ __device__ constexpr int quadrow(int x, int y) {
    if (x > y) { int t = x; x = y; y = t; }
    return 17 + x * 16 - x * (x - 1) / 2 + (y - x);     // np.triu_indices order
}

__host__ __device__ constexpr int krow16(int m, int g) {
    const int sh = 4 * g;
    if (m < 4)  return 1 + (m ^ sh);
    if (m < 8)  return 153 + ((m - 4) ^ sh);
    if (m < 12) { const int a = (m - 8) ^ sh; return quadrow(a, a); }
    if (m < 14) { const int u = m - 12; return quadrow((2*u) ^ sh, (2*u+1) ^ sh); }
    if (m < 30) {
        const int idx = m - 14, rep = idx >> 2, w = idx & 3;
        const int v = 2 * rep + 1;
        const int a = ((w == 1 || w == 3) ? 1 : 0);
        const int b = 2 * v + ((w == 1 || w == 2) ? 1 : 0);
        return quadrow(a ^ sh, b ^ sh);
    }
    if (m < 54) {
        const int idx = m - 30, rep = idx >> 2, w = idx & 3;
        const int u = rep & 1;
        const int v = 2 + 2 * (rep >> 1) + (rep & 1);
        const int d = u ^ v;
        const bool live = (d == 2) ? (g == 0 || g == 2) : (g == 0 || g == 1);
        if (!live) return -1;
        const int a = 2 * u + ((w == 1 || w == 3) ? 1 : 0);
        const int b = 2 * v + ((w == 1 || w == 2) ? 1 : 0);
        return quadrow(a ^ sh, b ^ sh);
    }
    return -1;
}

// ---------------- kernel 1: pack A fragments + c0 into ws --------------------
// 70 blocks x 64 threads: blockIdx = r*NCHUNK + c.
__global__ __launch_bounds__(64) void pack_A16_kernel(
    const float* __restrict__ coeff, const float* __restrict__ mask, char* __restrict__ ws)
{
    const int r = blockIdx.x / NCHUNK;
    const int c = blockIdx.x % NCHUNK;
    const int lane = threadIdx.x;
    const int d = lane & 15, g = lane >> 4;
    const float* cr = coeff + (size_t)r * NTERMS * LATENT;
    const float* mr = mask  + (size_t)r * NTERMS * LATENT;
    FragHE a;
    for (int e = 0; e < 8; ++e) {
        const int row = krow16(c * 8 + e, g);
        float v = 0.0f;
        if (row >= 0) v = cr[row * LATENT + d] * mr[row * LATENT + d] * (DT * ASCALE);
        a.e[e] = (_Float16)v;
    }
    reinterpret_cast<int4v*>(ws)[((size_t)r * NCHUNK + c) * 64 + lane] = a.i4;

    if (c == 0 && lane < LATENT) {
        float* c0p = reinterpret_cast<float*>(ws + WS_C0_OFF);
        c0p[r * LATENT + lane] = cr[lane] * mr[lane] * (DT * ASCALE);   // row 0
    }
}

// ---------------- kernel 2: main integration ----------------
// One wave = 16 trajectories x 4 k-groups. col=lane&15, g=lane>>4.
// Own 4-dim block in f32 (f32x4, packed-f32 math); other 12 h-values circulate
// as packed f16 pairs via 6 ds_bpermute (precomputed idx). Step loop unrolled.
template<bool USE_WS>
__global__ __launch_bounds__(256, 4) void sindy_f16_kernel(
    const float* __restrict__ h_t,    // [N, 16]
    const float* __restrict__ coeff,  // [10, 169, 16]
    const float* __restrict__ mask,   // [10, 169, 16]
    const char* __restrict__ ws,
    float* __restrict__ out,          // [N, 10, 16]
    int N, int ntiles)
{
    const int lane = threadIdx.x & 63;
    const int wid  = blockIdx.x * 4 + (threadIdx.x >> 6);
    if (wid >= NREP * ntiles) return;
    const int r    = wid / ntiles;
    const int tile = wid % ntiles;

    const int col = lane & 15;        // trajectory within tile; also A dim column
    const int g   = lane >> 4;        // k-group; sigma = XOR(4g)

    // broadcast indices (byte addr for ds_bpermute), computed once
    const int idx16 = (lane ^ 16) << 2;
    const int idx32 = (lane ^ 32) << 2;
    const int idx48 = (lane ^ 48) << 2;

    // ---- A fragments (28 VGPR, loop-invariant) ----
    int4v afi[NCHUNK];
    if constexpr (USE_WS) {
        const int4v* wa = reinterpret_cast<const int4v*>(ws);
        #pragma unroll
        for (int c = 0; c < NCHUNK; ++c)
            afi[c] = wa[((size_t)r * NCHUNK + c) * 64 + lane];
    } else {
        const float* cr = coeff + (size_t)r * NTERMS * LATENT;
        const float* mr = mask  + (size_t)r * NTERMS * LATENT;
        #pragma unroll
        for (int c = 0; c < NCHUNK; ++c) {
            FragHE a;
            #pragma unroll
            for (int e = 0; e < 8; ++e) {
                const int row = krow16(c * 8 + e, g);
                float v = 0.0f;
                if (row >= 0) v = cr[row * LATENT + col] * mr[row * LATENT + col] * (DT * ASCALE);
                a.e[e] = (_Float16)v;
            }
            afi[c] = a.i4;
        }
    }

    // ---- scaled constant column (ONE term), own dims 4g..4g+3 ----
    f32x4 c04;
    if constexpr (USE_WS) {
        const float4 v = *reinterpret_cast<const float4*>(
            ws + WS_C0_OFF + ((size_t)r * LATENT + 4 * g) * 4);
        c04[0] = v.x; c04[1] = v.y; c04[2] = v.z; c04[3] = v.w;
    } else {
        const float* cr = coeff + (size_t)r * NTERMS * LATENT;
        const float* mr = mask  + (size_t)r * NTERMS * LATENT;
        #pragma unroll
        for (int j = 0; j < 4; ++j) {
            const int d2 = 4 * g + j;
            c04[j] = cr[d2] * mr[d2] * (DT * ASCALE);
        }
    }

    // ---- own h block only: hq[j] = h_global[4g + j] (one float4) ----
    const int n = tile * 16 + col;
    f32x4 hq;
    {
        float4 q = make_float4(0.f, 0.f, 0.f, 0.f);
        if (n < N)
            q = *reinterpret_cast<const float4*>(h_t + (size_t)n * LATENT + 4 * g);
        hq[0] = q.x; hq[1] = q.y; hq[2] = q.z; hq[3] = q.w;
    }

    // ---- 10 sequential Euler steps, fully unrolled ----
    #pragma unroll
    for (int s = 0; s < NSTEPS; ++s) {
        // own pairs, then packed-f16 broadcast across the 4 g-groups
        h2 hp[8];
        hp[0] = pkrtz(hq[0], hq[1]);
        hp[1] = pkrtz(hq[2], hq[3]);
        hp[2] = bperm_h2(idx16, hp[0]);
        hp[3] = bperm_h2(idx16, hp[1]);
        hp[4] = bperm_h2(idx32, hp[0]);
        hp[5] = bperm_h2(idx32, hp[1]);
        hp[6] = bperm_h2(idx48, hp[0]);
        hp[7] = bperm_h2(idx48, hp[1]);

        // preload: acc = 1024*h_old + 1024*c0 (packed f32)
        f32x4 acc = hq * ASCALE + c04;

        FragH f;
        #define MM(C) acc = __builtin_amdgcn_mfma_f32_16x16x32_f16( \
            __builtin_bit_cast(half8, afi[C]), f.v, acc, 0, 0, 0);
        // c0: lin 0-3, sin 0-3 (own block f32)
        f.p[0] = hp[0]; f.p[1] = hp[1];
        f.p[2] = pkrtz(__sinf(hq[0]), __sinf(hq[1]));
        f.p[3] = pkrtz(__sinf(hq[2]), __sinf(hq[3]));
        MM(0)
        // c1: diag 0-3, within-pair crosses (own f32), odd-rep v=1 pkA
        f.p[0] = hp[0] * hp[0]; f.p[1] = hp[1] * hp[1];
        f.p[2] = pkrtz(hq[0] * hq[1], hq[2] * hq[3]);
        f.p[3] = hp[0] * hp[1];
        MM(1)
        // c2
        f.p[0] = hp[0] * SW(hp[1]); f.p[1] = hp[0] * hp[3];
        f.p[2] = hp[0] * SW(hp[3]); f.p[3] = hp[0] * hp[5];
        MM(2)
        // c3
        f.p[0] = hp[0] * SW(hp[5]); f.p[1] = hp[0] * hp[7];
        f.p[2] = hp[0] * SW(hp[7]); f.p[3] = hp[0] * hp[2];
        MM(3)
        // c4
        f.p[0] = hp[0] * SW(hp[2]); f.p[1] = hp[1] * hp[3];
        f.p[2] = hp[1] * SW(hp[3]); f.p[3] = hp[0] * hp[4];
        MM(4)
        // c5
        f.p[0] = hp[0] * SW(hp[4]); f.p[1] = hp[1] * hp[5];
        f.p[2] = hp[1] * SW(hp[5]); f.p[3] = hp[0] * hp[6];
        MM(5)
        // c6
        f.p[0] = hp[0] * SW(hp[6]); f.p[1] = hp[1] * hp[7];
        f.p[2] = hp[1] * SW(hp[7]); f.p[3] = (h2)(_Float16)0;
        MM(6)
        #undef MM

        // scale back (exact pow2, packed f32): new own h
        hq = acc * INV_ASCALE;
    }

    // ---- store: out[n][r][4g+j] = own h ----
    if (n < N) {
        float* op = out + ((size_t)n * NREP + r) * LATENT + 4 * g;
        *reinterpret_cast<float4*>(op) = make_float4(hq[0], hq[1], hq[2], hq[3]);
    }
}

extern "C" void kernel_launch(void* const* d_in, const int* in_sizes, int n_in,
                              void* d_out, int out_size, void* d_ws, size_t ws_size,
                              hipStream_t stream) {
    const float* h_t   = (const float*)d_in[0];
    const float* coeff = (const float*)d_in[1];
    const float* mask  = (const float*)d_in[2];
    float* out = (float*)d_out;

    const int N = in_sizes[0] / LATENT;          // 50000
    const int ntiles = (N + 15) / 16;            // 3125
    const int nwaves = NREP * ntiles;            // 31250
    const int nblocks = (nwaves + 3) / 4;

    if (ws_size >= (size_t)WS_TOTAL) {
        pack_A16_kernel<<<dim3(NREP * NCHUNK), dim3(64), 0, stream>>>(coeff, mask, (char*)d_ws);
        sindy_f16_kernel<true><<<dim3(nblocks), dim3(256), 0, stream>>>(
            h_t, coeff, mask, (const char*)d_ws, out, N, ntiles);
    } else {
        sindy_f16_kernel<false><<<dim3(nblocks), dim3(256), 0, stream>>>(
            h_t, coeff, mask, (const char*)d_ws, out, N, ntiles);
    }
}